// Round 8
// baseline (472.279 us; speedup 1.0000x reference)
//
#include <hip/hip_runtime.h>
#include <math.h>

#define S_LEN   16384
#define NCONV   128
#define NBATCH  256
#define TPB     512    // 8 waves; one conv per wave
#define NGRP    16     // conv groups per row
#define ZSLOT   16384  // sh[ZSLOT] = sh[ZSLOT+1] = 0.0f: OOB clamp target
#define DSTRIDE 20

typedef float __attribute__((address_space(1))) as1_float;
typedef float __attribute__((address_space(3))) as3_float;
typedef __attribute__((ext_vector_type(2))) float f2;

// ---------------- setup: descriptors + LPT snake balancing ----------------
__global__ void setup_desc(const int* __restrict__ ks, const int* __restrict__ dil,
                           const int* __restrict__ pad, const float* __restrict__ W,
                           const float* __restrict__ bias, int* __restrict__ ws)
{
  __shared__ int cost_s[NCONV];
  const int ci = threadIdx.x;  // blockDim == 128
  const int is64 = (ks[1] == 0);
  const int k = is64 ? ks[2 * ci]  : ks[ci];
  const int d = is64 ? dil[2 * ci] : dil[ci];
  const int p = is64 ? pad[2 * ci] : pad[ci];
  const int L = S_LEN + 2 * p - d * (k - 1);
  const int A = L / d, B = L - A * d;
  const int cost = (d >= 2) ? (L * (k + 8)) / 2 + k * d : L * (k + 6);
  cost_s[ci] = cost;
  __syncthreads();
  int rank = 0;
  for (int j = 0; j < NCONV; ++j) {
    const int cj = cost_s[j];
    rank += (cj > cost) || (cj == cost && j < ci);
  }
  const int lvl = rank >> 4;          // 8 wave-levels
  int gg = rank & 15;                 // 16 groups
  if (lvl & 1) gg = 15 - gg;          // snake-deal -> balanced blocks
  int* dsc = ws + (gg * 8 + lvl) * DSTRIDE;
  dsc[0] = d; dsc[1] = p; dsc[2] = A; dsc[3] = B; dsc[4] = ci; dsc[7] = k;
  ((float*)dsc)[5] = 1.0f / (float)L;
  ((float*)dsc)[6] = bias[ci];
#pragma unroll
  for (int t = 0; t < 11; ++t) ((float*)dsc)[8 + t] = W[ci * 11 + t];
}

// ---------------- helpers ----------------
__device__ __forceinline__ float sgpr_f(float v) {
  return __int_as_float(__builtin_amdgcn_readfirstlane(__float_as_int(v)));
}
__device__ __forceinline__ int sgpr_i(int v) {
  return __builtin_amdgcn_readfirstlane(v);
}
__device__ __forceinline__ float rcpf(float x) { return __builtin_amdgcn_rcpf(x); }

// exact floor(num/d), num in [0, ~2^22), rd ~= 1/d; NO v_div sequences
__device__ __forceinline__ int divq(int num, float rd, int d) {
  int q = (int)((float)num * rd);
  q -= (q * d > num);
  q += ((q + 1) * d <= num);
  return q;
}

__device__ __forceinline__ float lds_at(const float* sh, int pos) {
  unsigned idx = (unsigned)pos;
  idx = idx > (unsigned)ZSLOT ? (unsigned)ZSLOT : idx;
  return sh[idx];
}

__device__ __forceinline__ f2 pfma(f2 a, f2 b, f2 c) {
#if __has_builtin(__builtin_elementwise_fma)
  return __builtin_elementwise_fma(a, b, c);
#else
  f2 r; r.x = fmaf(a.x, b.x, c.x); r.y = fmaf(a.y, b.y, c.y); return r;
#endif
}

// ---------------- scalar rotate walk (K=11 fixed; w zero-padded => exact) ----
template <bool SAFE, bool EXACT>
__device__ __forceinline__ void walk11s(
    const float* sh, const float* w, float bval,
    int d, int sb, int q0, int q1, float& mx, int& cnt)
{
  const int n = q1 - q0;
  if (n <= 0) return;
  float win[11];
  int pos = sb + q0 * d;
#pragma unroll
  for (int t = 0; t < 10; ++t) {
    win[t] = SAFE ? lds_at(sh, pos) : sh[pos];
    pos += d;
  }
  for (int i = 0; i < n; i += 11) {
#pragma unroll
    for (int s = 0; s < 11; ++s) {
      win[(s + 10) % 11] = SAFE ? lds_at(sh, pos) : sh[pos];
      pos += d;
      float a = bval;
#pragma unroll
      for (int t = 0; t < 11; ++t) a = fmaf(w[t], win[(s + t) % 11], a);
      if (EXACT || (i + s < n)) { mx = fmaxf(mx, a); cnt += (a >= 0.f); }
    }
  }
}

__device__ __forceinline__ void cls11(
    const float* sh, const float* w, float bval,
    int d, float rd, int p, int r, int q0, int q1, float& mx, int& cnt)
{
  if (q1 <= q0) return;
  const int qlo = (p > r) ? divq(p - r + d - 1, rd, d) : 0;
  const int qhi = divq(S_LEN - 1 - r + p, rd, d) - 10;
  int i0 = min(max(qlo, q0), q1);
  int i1 = min(qhi + 1, q1); if (i1 < i0) i1 = i0;
  const int nI = i1 - i0;
  const int nE = nI - nI % 11;
  walk11s<true,  false>(sh, w, bval, d, r - p, q0, i0, mx, cnt);
  walk11s<false, true >(sh, w, bval, d, r - p, i0, i0 + nE, mx, cnt);
  walk11s<true,  false>(sh, w, bval, d, r - p, i0 + nE, q1, mx, cnt);
}

__device__ __forceinline__ void one_out11(
    const float* sh, const float* w, float bval,
    int d, int p, int j, float& mx, int& cnt)
{
  float a = bval;
  int pos = j - p;
#pragma unroll
  for (int t = 0; t < 11; ++t) { a = fmaf(w[t], lds_at(sh, pos), a); pos += d; }
  mx = fmaxf(mx, a);
  cnt += (a >= 0.f);
}

// split class r's [0,Q) over 64 lanes with mod-32 stagger
__device__ __forceinline__ void scalar_split11(
    const float* sh, const float* w, float bval,
    int d, float rd, int p, int r, int Q, int lane, float& mx, int& cnt)
{
  if (Q <= 0) return;
  const int v  = lane;
  const int mm = Q >> 6;
  const int sA = (mm >= 32) ? (v & 31) : (((v & 31) * mm) >> 5);
  const int vB = v + 1;
  const int sB = (mm >= 32) ? (vB & 31) : (((vB & 31) * mm) >> 5);
  const int q0 = (int)(((long long)Q * v) >> 6) + sA;
  const int q1 = (v == 63) ? Q : (int)(((long long)Q * vB) >> 6) + sB;
  cls11(sh, w, bval, d, rd, p, r, q0, q1, mx, cnt);
}

// ---------------- pair walk: classes (r0, r0+1) -> one ds_read2_b32 + k
// v_pk_fma_f32 per TWO outputs; one-iteration load lookahead ----------------
template <int K, bool EXACT>
__device__ __forceinline__ void pwalk(
    const float* sh, const float* w, float bval,
    int d, int sb, int q0, int q1,
    float& mxa, float& mxb, int& ca, int& cb)
{
  const int n = q1 - q0;
  if (n <= 0) return;
  f2 win[K];
  int pos = sb + q0 * d;
#pragma unroll
  for (int t = 0; t < K - 1; ++t) {           // in-bounds by construction
    f2 vv; vv.x = sh[pos]; vv.y = sh[pos + 1];
    win[t] = vv; pos += d;
  }
  f2 pf; pf.x = sh[pos]; pf.y = sh[pos + 1]; pos += d;
  for (int i = 0; i < n; i += K) {
#pragma unroll
    for (int s = 0; s < K; ++s) {
      const f2 cur = pf;
      {                                       // lookahead (clamped over-read)
        unsigned idx = (unsigned)pos;
        idx = idx > (unsigned)ZSLOT ? (unsigned)ZSLOT : idx;
        f2 vv; vv.x = sh[idx]; vv.y = sh[idx + 1];
        pf = vv;
      }
      pos += d;
      f2 a0; a0.x = bval; a0.y = bval;        // split accumulators: shorter
      f2 a1; a1.x = 0.f;  a1.y = 0.f;         // dependency chains
#pragma unroll
      for (int t = 0; t < K; ++t) {
        const f2 xv = (t == K - 1) ? cur : win[(s + t) % K];
        f2 wv; wv.x = w[t]; wv.y = w[t];
        if (t & 1) a1 = pfma(wv, xv, a1);
        else       a0 = pfma(wv, xv, a0);
      }
      win[(s + K - 1) % K] = cur;
      const f2 a = a0 + a1;
      if (EXACT || (i + s < n)) {
        mxa = fmaxf(mxa, a.x); mxb = fmaxf(mxb, a.y);
        ca += (a.x >= 0.f);    cb += (a.y >= 0.f);
      }
    }
  }
}

// pair column (r0, r0+1), q in [q0,q1): scalar clamped boundaries + pair interior
template <int K>
__device__ __forceinline__ void pc(
    const float* sh, const float* w, float bval,
    int d, float rd, int p, int r0, int q0, int q1,
    float& mxa, float& mxb, int& ca, int& cb)
{
  if (q1 <= q0) return;
  const int qlo = (p > r0) ? divq(p - r0 + d - 1, rd, d) : 0;
  const int qhi = divq(S_LEN - 2 - r0 + p, rd, d) - (K - 1);
  int i0 = min(max(qlo, q0), q1);
  int i1 = min(qhi + 1, q1); if (i1 < i0) i1 = i0;
  const int nI = i1 - i0;
  const int nE = nI - nI % K;
  walk11s<true, false>(sh, w, bval, d, r0 - p,     q0, i0, mxa, ca);
  walk11s<true, false>(sh, w, bval, d, r0 + 1 - p, q0, i0, mxb, cb);
  pwalk<K, true >(sh, w, bval, d, r0 - p, i0, i0 + nE, mxa, mxb, ca, cb);
  pwalk<K, false>(sh, w, bval, d, r0 - p, i0 + nE, i1, mxa, mxb, ca, cb);
  walk11s<true, false>(sh, w, bval, d, r0 - p,     i1, q1, mxa, ca);
  walk11s<true, false>(sh, w, bval, d, r0 + 1 - p, i1, q1, mxb, cb);
}

template <int K>
__device__ __forceinline__ void conv_wave(
    const float* sh, const float* w, float bval,
    int d, float rd, int p, int A, int B, int lane,
    float& mxa, float& mxb, int& ca, int& cb)
{
  if (d == 1) {  // single class; ~9% of convs stay scalar
    scalar_split11(sh, w, bval, 1, 1.0f, p, 0, A, lane, mxa, ca);
    return;
  }
  const int npair = d >> 1;
  if (npair >= 64) {
    // whole pair-columns per lane (adjacent lanes -> adjacent addresses)
    for (int g = lane; g < npair; g += 64) {
      const int r0 = 2 * g;
      const int Q0 = A + (r0 < B);        // = ceil((L-r)/d), 0 when r >= L
      const int Q1 = A + (r0 + 1 < B);
      pc<K>(sh, w, bval, d, rd, p, r0, 0, Q1, mxa, mxb, ca, cb);
      if (Q0 > Q1) one_out11(sh, w, bval, d, p, r0 + A * d, mxa, ca);
    }
  } else {
    // split each pair-column's q-range among its lanes (staggered)
    const float rdp = rcpf((float)npair);
    int v  = (int)((float)lane * rdp);
    int g2 = lane - v * npair;
    if (g2 < 0)           { --v; g2 += npair; }
    else if (g2 >= npair) { ++v; g2 -= npair; }
    const int nv = divq(63 - g2, rdp, npair) + 1;
    const int r0 = 2 * g2;
    const int Q0 = A + (r0 < B);
    const int Q1 = A + (r0 + 1 < B);
    const float rn = rcpf((float)nv);
    const int mm = (int)((float)Q1 * rn);
    const int sA = (mm >= 32) ? (v & 31) : (((v & 31) * mm) >> 5);
    const int vB = v + 1;
    const int sB = (mm >= 32) ? (vB & 31) : (((vB & 31) * mm) >> 5);
    const int q0 = (int)((float)(Q1 * v) * rn) + sA;       // v==0 -> 0
    const int q1 = (v == nv - 1) ? Q1 : (int)((float)(Q1 * vB) * rn) + sB;
    pc<K>(sh, w, bval, d, rd, p, r0, q0, q1, mxa, mxb, ca, cb);
    if (v == nv - 1 && Q0 > Q1)
      one_out11(sh, w, bval, d, p, r0 + A * d, mxa, ca);
  }
  if (d & 1)  // odd d: unpaired last class, split across all lanes
    scalar_split11(sh, w, bval, d, rd, p, d - 1, A + ((d - 1) < B), lane, mxa, ca);
}

// ---------------- hot kernel ----------------
__global__ __launch_bounds__(TPB, 4) void rocket_feats(
    const float* __restrict__ x, const int* __restrict__ ws,
    float* __restrict__ out)
{
  __shared__ float sh[S_LEN + 2];  // 64.5KB -> 2 blocks/CU (LDS-capped)

  const int tid  = threadIdx.x;
  const int blk  = blockIdx.x;   // blk = b*16 + g: row's blocks dispatch-adjacent
  const int g    = blk & 15;
  const int b    = blk >> 4;
  const int lane = tid & 63, wid = tid >> 6;  // wid in [0,8)

  const float* xrow = x + (size_t)b * S_LEN;
  {
    const float* gb = xrow + lane * 4;
#pragma unroll
    for (int c = 0; c < 8; ++c) {
      const int off = (wid * 8 + c) * 256;  // floats
      __builtin_amdgcn_global_load_lds((const as1_float*)(gb + off),
                                       (as3_float*)(sh + off), 16, 0, 0);
    }
  }
  if (tid == 0) { sh[ZSLOT] = 0.f; sh[ZSLOT + 1] = 0.f; }

  // wave-uniform descriptor -> SGPRs (overlaps with staging)
  const int* dsc = ws + (g * 8 + wid) * DSTRIDE;
  const int d  = sgpr_i(dsc[0]);
  const int p  = sgpr_i(dsc[1]);
  const int A  = sgpr_i(dsc[2]);
  const int B  = sgpr_i(dsc[3]);
  const int ci = sgpr_i(dsc[4]);
  const int k  = sgpr_i(dsc[7]);
  const float invL = sgpr_f(((const float*)dsc)[5]);
  const float bval = sgpr_f(((const float*)dsc)[6]);
  float w[11];
#pragma unroll
  for (int t = 0; t < 11; ++t) w[t] = sgpr_f(((const float*)dsc)[8 + t]);

  __syncthreads();  // only barrier

  const float rd = rcpf((float)d);
  float mxa = -INFINITY, mxb = -INFINITY;
  int ca = 0, cb = 0;

  if (k == 7)      conv_wave<7 >(sh, w, bval, d, rd, p, A, B, lane, mxa, mxb, ca, cb);
  else if (k == 9) conv_wave<9 >(sh, w, bval, d, rd, p, A, B, lane, mxa, mxb, ca, cb);
  else             conv_wave<11>(sh, w, bval, d, rd, p, A, B, lane, mxa, mxb, ca, cb);

  float mx = fmaxf(mxa, mxb);
  int cnt = ca + cb;
#pragma unroll
  for (int off = 32; off > 0; off >>= 1) {
    mx = fmaxf(mx, __shfl_down(mx, off, 64));
    cnt += __shfl_down(cnt, off, 64);
  }
  if (lane == 0) {
    out[(size_t)b * (2 * NCONV) + 2 * ci]     = mx;
    out[(size_t)b * (2 * NCONV) + 2 * ci + 1] = (float)cnt * invL;
  }
}

extern "C" void kernel_launch(void* const* d_in, const int* in_sizes, int n_in,
                              void* d_out, int out_size, void* d_ws, size_t ws_size,
                              hipStream_t stream) {
  const float* x    = (const float*)d_in[0];
  const float* W    = (const float*)d_in[1];
  const float* bias = (const float*)d_in[2];
  const int*   ks   = (const int*)d_in[3];
  const int*   dil  = (const int*)d_in[4];
  const int*   pad  = (const int*)d_in[5];
  float* out = (float*)d_out;
  int*   ws  = (int*)d_ws;  // 128*20*4 = 10240 bytes

  hipLaunchKernelGGL(setup_desc, dim3(1), dim3(NCONV), 0, stream,
                     ks, dil, pad, W, bias, ws);
  hipLaunchKernelGGL(rocket_feats, dim3(NBATCH * NGRP), dim3(TPB), 0, stream,
                     x, ws, out);
}

// Round 9
// 343.042 us; speedup vs baseline: 1.3767x; 1.3767x over previous
//
#include <hip/hip_runtime.h>
#include <math.h>

#define S_LEN   16384
#define NCONV   128
#define NBATCH  256
#define TPB     1024   // 16 waves; one conv per wave
#define NGRP    8      // conv groups per row (16 convs each)
#define ZSLOT   16384  // sh[ZSLOT] = sh[ZSLOT+1] = 0.0f: OOB clamp target
#define DSTRIDE 20

typedef float __attribute__((address_space(1))) as1_float;
typedef float __attribute__((address_space(3))) as3_float;
typedef __attribute__((ext_vector_type(2))) float f2;

// ---------------- setup: descriptors + LPT snake balancing ----------------
__global__ void setup_desc(const int* __restrict__ ks, const int* __restrict__ dil,
                           const int* __restrict__ pad, const float* __restrict__ W,
                           const float* __restrict__ bias, int* __restrict__ ws)
{
  __shared__ int cost_s[NCONV];
  const int ci = threadIdx.x;  // blockDim == 128
  const int is64 = (ks[1] == 0);
  const int k = is64 ? ks[2 * ci]  : ks[ci];
  const int d = is64 ? dil[2 * ci] : dil[ci];
  const int p = is64 ? pad[2 * ci] : pad[ci];
  const int L = S_LEN + 2 * p - d * (k - 1);
  const int A = L / d, B = L - A * d;
  const int cost = (d >= 2) ? (L * (k + 8)) / 2 + k * d : L * (k + 6);
  cost_s[ci] = cost;
  __syncthreads();
  int rank = 0;
  for (int j = 0; j < NCONV; ++j) {
    const int cj = cost_s[j];
    rank += (cj > cost) || (cj == cost && j < ci);
  }
  const int lvl = rank >> 3;          // 16 wave-levels
  int gg = rank & 7;                  // 8 groups
  if (lvl & 1) gg = 7 - gg;           // snake-deal -> balanced blocks
  int* dsc = ws + (gg * 16 + lvl) * DSTRIDE;
  dsc[0] = d; dsc[1] = p; dsc[2] = A; dsc[3] = B; dsc[4] = ci; dsc[7] = k;
  ((float*)dsc)[5] = 1.0f / (float)L;
  ((float*)dsc)[6] = bias[ci];
#pragma unroll
  for (int t = 0; t < 11; ++t) ((float*)dsc)[8 + t] = W[ci * 11 + t];
}

// ---------------- helpers ----------------
__device__ __forceinline__ float sgpr_f(float v) {
  return __int_as_float(__builtin_amdgcn_readfirstlane(__float_as_int(v)));
}
__device__ __forceinline__ int sgpr_i(int v) {
  return __builtin_amdgcn_readfirstlane(v);
}
__device__ __forceinline__ float rcpf(float x) { return __builtin_amdgcn_rcpf(x); }

// exact floor(num/d), num in [0, ~2^22), rd ~= 1/d; NO v_div sequences
__device__ __forceinline__ int divq(int num, float rd, int d) {
  int q = (int)((float)num * rd);
  q -= (q * d > num);
  q += ((q + 1) * d <= num);
  return q;
}

__device__ __forceinline__ float lds_at(const float* sh, int pos) {
  unsigned idx = (unsigned)pos;
  idx = idx > (unsigned)ZSLOT ? (unsigned)ZSLOT : idx;
  return sh[idx];
}

__device__ __forceinline__ f2 pfma(f2 a, f2 b, f2 c) {
#if __has_builtin(__builtin_elementwise_fma)
  return __builtin_elementwise_fma(a, b, c);
#else
  f2 r; r.x = fmaf(a.x, b.x, c.x); r.y = fmaf(a.y, b.y, c.y); return r;
#endif
}
__device__ __forceinline__ f2 pmax(f2 a, f2 b) {
#if __has_builtin(__builtin_elementwise_max)
  return __builtin_elementwise_max(a, b);
#else
  f2 r; r.x = fmaxf(a.x, b.x); r.y = fmaxf(a.y, b.y); return r;
#endif
}

// ---------------- scalar rotate walk (K=11 fixed; w zero-padded => exact) ----
template <bool SAFE, bool EXACT>
__device__ __forceinline__ void walk11s(
    const float* sh, const float* w, float bval,
    int d, int sb, int q0, int q1, float& mx, int& cnt)
{
  const int n = q1 - q0;
  if (n <= 0) return;
  float win[11];
  int pos = sb + q0 * d;
#pragma unroll
  for (int t = 0; t < 10; ++t) {
    win[t] = SAFE ? lds_at(sh, pos) : sh[pos];
    pos += d;
  }
  for (int i = 0; i < n; i += 11) {
#pragma unroll
    for (int s = 0; s < 11; ++s) {
      win[(s + 10) % 11] = SAFE ? lds_at(sh, pos) : sh[pos];
      pos += d;
      float a = bval;
#pragma unroll
      for (int t = 0; t < 11; ++t) a = fmaf(w[t], win[(s + t) % 11], a);
      if (EXACT || (i + s < n)) { mx = fmaxf(mx, a); cnt += (a >= 0.f); }
    }
  }
}

__device__ __forceinline__ void cls11(
    const float* sh, const float* w, float bval,
    int d, float rd, int p, int r, int q0, int q1, float& mx, int& cnt)
{
  if (q1 <= q0) return;
  const int qlo = (p > r) ? divq(p - r + d - 1, rd, d) : 0;
  const int qhi = divq(S_LEN - 1 - r + p, rd, d) - 10;
  int i0 = min(max(qlo, q0), q1);
  int i1 = min(qhi + 1, q1); if (i1 < i0) i1 = i0;
  const int nI = i1 - i0;
  const int nE = nI - nI % 11;
  walk11s<true,  false>(sh, w, bval, d, r - p, q0, i0, mx, cnt);
  walk11s<false, true >(sh, w, bval, d, r - p, i0, i0 + nE, mx, cnt);
  walk11s<true,  false>(sh, w, bval, d, r - p, i0 + nE, q1, mx, cnt);
}

__device__ __forceinline__ void one_out11(
    const float* sh, const float* w, float bval,
    int d, int p, int j, float& mx, int& cnt)
{
  float a = bval;
  int pos = j - p;
#pragma unroll
  for (int t = 0; t < 11; ++t) { a = fmaf(w[t], lds_at(sh, pos), a); pos += d; }
  mx = fmaxf(mx, a);
  cnt += (a >= 0.f);
}

// split class r's [0,Q) over 64 lanes with mod-32 stagger
__device__ __forceinline__ void scalar_split11(
    const float* sh, const float* w, float bval,
    int d, float rd, int p, int r, int Q, int lane, float& mx, int& cnt)
{
  if (Q <= 0) return;
  const int v  = lane;
  const int mm = Q >> 6;
  const int sA = (mm >= 32) ? (v & 31) : (((v & 31) * mm) >> 5);
  const int vB = v + 1;
  const int sB = (mm >= 32) ? (vB & 31) : (((vB & 31) * mm) >> 5);
  const int q0 = (int)(((long long)Q * v) >> 6) + sA;
  const int q1 = (v == 63) ? Q : (int)(((long long)Q * vB) >> 6) + sB;
  cls11(sh, w, bval, d, rd, p, r, q0, q1, mx, cnt);
}

// ---------------- pair walk: classes (r0, r0+1) -> one ds_read2_b32 + k
// v_pk_fma_f32 per TWO outputs; one-iteration load lookahead ----------------
template <int K, bool EXACT>
__device__ __forceinline__ void pwalk(
    const float* sh, const float* w, float bval,
    int d, int sb, int q0, int q1,
    f2& mxv, int& ca, int& cb)
{
  const int n = q1 - q0;
  if (n <= 0) return;
  f2 win[K];
  int pos = sb + q0 * d;
#pragma unroll
  for (int t = 0; t < K - 1; ++t) {           // in-bounds by construction
    f2 vv; vv.x = sh[pos]; vv.y = sh[pos + 1];
    win[t] = vv; pos += d;
  }
  f2 pf; pf.x = sh[pos]; pf.y = sh[pos + 1]; pos += d;
  for (int i = 0; i < n; i += K) {
#pragma unroll
    for (int s = 0; s < K; ++s) {
      const f2 cur = pf;
      {                                       // lookahead (clamped over-read)
        unsigned idx = (unsigned)pos;
        idx = idx > (unsigned)ZSLOT ? (unsigned)ZSLOT : idx;
        f2 vv; vv.x = sh[idx]; vv.y = sh[idx + 1];
        pf = vv;
      }
      pos += d;
      f2 a0; a0.x = bval; a0.y = bval;        // split accumulators: shorter
      f2 a1; a1.x = 0.f;  a1.y = 0.f;         // dependency chains
#pragma unroll
      for (int t = 0; t < K; ++t) {
        const f2 xv = (t == K - 1) ? cur : win[(s + t) % K];
        f2 wv; wv.x = w[t]; wv.y = w[t];
        if (t & 1) a1 = pfma(wv, xv, a1);
        else       a0 = pfma(wv, xv, a0);
      }
      win[(s + K - 1) % K] = cur;
      const f2 a = a0 + a1;
      if (EXACT || (i + s < n)) {
        mxv = pmax(mxv, a);
        ca += (a.x >= 0.f);
        cb += (a.y >= 0.f);
      }
    }
  }
}

// pair column (r0, r0+1), q in [q0,q1): scalar clamped boundaries + pair interior
template <int K>
__device__ __forceinline__ void pc(
    const float* sh, const float* w, float bval,
    int d, float rd, int p, int r0, int q0, int q1,
    f2& mxv, float& mxs, int& ca, int& cb)
{
  if (q1 <= q0) return;
  const int qlo = (p > r0) ? divq(p - r0 + d - 1, rd, d) : 0;
  const int qhi = divq(S_LEN - 2 - r0 + p, rd, d) - (K - 1);
  int i0 = min(max(qlo, q0), q1);
  int i1 = min(qhi + 1, q1); if (i1 < i0) i1 = i0;
  const int nI = i1 - i0;
  const int nE = nI - nI % K;
  walk11s<true, false>(sh, w, bval, d, r0 - p,     q0, i0, mxs, ca);
  walk11s<true, false>(sh, w, bval, d, r0 + 1 - p, q0, i0, mxs, cb);
  pwalk<K, true >(sh, w, bval, d, r0 - p, i0, i0 + nE, mxv, ca, cb);
  pwalk<K, false>(sh, w, bval, d, r0 - p, i0 + nE, i1, mxv, ca, cb);
  walk11s<true, false>(sh, w, bval, d, r0 - p,     i1, q1, mxs, ca);
  walk11s<true, false>(sh, w, bval, d, r0 + 1 - p, i1, q1, mxs, cb);
}

template <int K>
__device__ __forceinline__ void conv_wave(
    const float* sh, const float* w, float bval,
    int d, float rd, int p, int A, int B, int lane,
    f2& mxv, float& mxs, int& ca, int& cb)
{
  if (d == 1) {  // single class; ~9% of convs stay scalar
    scalar_split11(sh, w, bval, 1, 1.0f, p, 0, A, lane, mxs, ca);
    return;
  }
  const int npair = d >> 1;
  if (npair >= 64) {
    // whole pair-columns per lane (adjacent lanes -> adjacent addresses)
    for (int g = lane; g < npair; g += 64) {
      const int r0 = 2 * g;
      const int Q0 = A + (r0 < B);        // = ceil((L-r)/d), 0 when r >= L
      const int Q1 = A + (r0 + 1 < B);
      pc<K>(sh, w, bval, d, rd, p, r0, 0, Q1, mxv, mxs, ca, cb);
      if (Q0 > Q1) one_out11(sh, w, bval, d, p, r0 + A * d, mxs, ca);
    }
  } else {
    // split each pair-column's q-range among its lanes (staggered)
    const float rdp = rcpf((float)npair);
    int v  = (int)((float)lane * rdp);
    int g2 = lane - v * npair;
    if (g2 < 0)           { --v; g2 += npair; }
    else if (g2 >= npair) { ++v; g2 -= npair; }
    const int nv = divq(63 - g2, rdp, npair) + 1;
    const int r0 = 2 * g2;
    const int Q0 = A + (r0 < B);
    const int Q1 = A + (r0 + 1 < B);
    const float rn = rcpf((float)nv);
    const int mm = (int)((float)Q1 * rn);
    const int sA = (mm >= 32) ? (v & 31) : (((v & 31) * mm) >> 5);
    const int vB = v + 1;
    const int sB = (mm >= 32) ? (vB & 31) : (((vB & 31) * mm) >> 5);
    const int q0 = (int)((float)(Q1 * v) * rn) + sA;       // v==0 -> 0
    const int q1 = (v == nv - 1) ? Q1 : (int)((float)(Q1 * vB) * rn) + sB;
    pc<K>(sh, w, bval, d, rd, p, r0, q0, q1, mxv, mxs, ca, cb);
    if (v == nv - 1 && Q0 > Q1)
      one_out11(sh, w, bval, d, p, r0 + A * d, mxs, ca);
  }
  if (d & 1)  // odd d: unpaired last class, split across all lanes
    scalar_split11(sh, w, bval, d, rd, p, d - 1, A + ((d - 1) < B), lane, mxs, ca);
}

// ---------------- hot kernel ----------------
__global__ __launch_bounds__(TPB, 8) void rocket_feats(
    const float* __restrict__ x, const int* __restrict__ ws,
    float* __restrict__ out)
{
  __shared__ float sh[S_LEN + 2];  // 64.5KB -> 2 blocks/CU, 32 waves/CU

  const int tid  = threadIdx.x;
  const int blk  = blockIdx.x;   // blk = b*8 + g: row's blocks dispatch-adjacent
  const int g    = blk & 7;
  const int b    = blk >> 3;
  const int lane = tid & 63, wid = tid >> 6;  // wid in [0,16)

  const float* xrow = x + (size_t)b * S_LEN;
  {
    const float* gb = xrow + lane * 4;
#pragma unroll
    for (int c = 0; c < 4; ++c) {
      const int off = (wid * 4 + c) * 256;  // floats
      __builtin_amdgcn_global_load_lds((const as1_float*)(gb + off),
                                       (as3_float*)(sh + off), 16, 0, 0);
    }
  }
  if (tid == 0) { sh[ZSLOT] = 0.f; sh[ZSLOT + 1] = 0.f; }

  // wave-uniform descriptor -> SGPRs (overlaps with staging)
  const int* dsc = ws + (g * 16 + wid) * DSTRIDE;
  const int d  = sgpr_i(dsc[0]);
  const int p  = sgpr_i(dsc[1]);
  const int A  = sgpr_i(dsc[2]);
  const int B  = sgpr_i(dsc[3]);
  const int ci = sgpr_i(dsc[4]);
  const int k  = sgpr_i(dsc[7]);
  const float invL = sgpr_f(((const float*)dsc)[5]);
  const float bval = sgpr_f(((const float*)dsc)[6]);
  float w[11];
#pragma unroll
  for (int t = 0; t < 11; ++t) w[t] = sgpr_f(((const float*)dsc)[8 + t]);

  __syncthreads();  // only barrier

  const float rd = rcpf((float)d);
  f2 mxv; mxv.x = -INFINITY; mxv.y = -INFINITY;
  float mxs = -INFINITY;
  int ca = 0, cb = 0;

  if (k == 7)      conv_wave<7 >(sh, w, bval, d, rd, p, A, B, lane, mxv, mxs, ca, cb);
  else if (k == 9) conv_wave<9 >(sh, w, bval, d, rd, p, A, B, lane, mxv, mxs, ca, cb);
  else             conv_wave<11>(sh, w, bval, d, rd, p, A, B, lane, mxv, mxs, ca, cb);

  float mx = fmaxf(fmaxf(mxv.x, mxv.y), mxs);
  int cnt = ca + cb;
#pragma unroll
  for (int off = 32; off > 0; off >>= 1) {
    mx = fmaxf(mx, __shfl_down(mx, off, 64));
    cnt += __shfl_down(cnt, off, 64);
  }
  if (lane == 0) {
    out[(size_t)b * (2 * NCONV) + 2 * ci]     = mx;
    out[(size_t)b * (2 * NCONV) + 2 * ci + 1] = (float)cnt * invL;
  }
}

extern "C" void kernel_launch(void* const* d_in, const int* in_sizes, int n_in,
                              void* d_out, int out_size, void* d_ws, size_t ws_size,
                              hipStream_t stream) {
  const float* x    = (const float*)d_in[0];
  const float* W    = (const float*)d_in[1];
  const float* bias = (const float*)d_in[2];
  const int*   ks   = (const int*)d_in[3];
  const int*   dil  = (const int*)d_in[4];
  const int*   pad  = (const int*)d_in[5];
  float* out = (float*)d_out;
  int*   ws  = (int*)d_ws;  // 128*20*4 = 10240 bytes

  hipLaunchKernelGGL(setup_desc, dim3(1), dim3(NCONV), 0, stream,
                     ks, dil, pad, W, bias, ws);
  hipLaunchKernelGGL(rocket_feats, dim3(NBATCH * NGRP), dim3(TPB), 0, stream,
                     x, ws, out);
}

// Round 10
// 342.652 us; speedup vs baseline: 1.3783x; 1.0011x over previous
//
#include <hip/hip_runtime.h>
#include <math.h>

#define S_LEN   16384
#define NCONV   128
#define NBATCH  256
#define TPB     1024   // 16 waves; one conv per wave
#define NGRP    8      // conv groups per row (16 convs each)
#define ZSLOT   16384  // sh[ZSLOT] = sh[ZSLOT+1] = 0.0f: OOB clamp target
#define DSTRIDE 20

typedef float __attribute__((address_space(1))) as1_float;
typedef float __attribute__((address_space(3))) as3_float;
typedef __attribute__((ext_vector_type(2))) float f2;

// ---------------- setup: descriptors + LPT snake balancing ----------------
__global__ void setup_desc(const int* __restrict__ ks, const int* __restrict__ dil,
                           const int* __restrict__ pad, const float* __restrict__ W,
                           const float* __restrict__ bias, int* __restrict__ ws)
{
  __shared__ int cost_s[NCONV];
  const int ci = threadIdx.x;  // blockDim == 128
  const int is64 = (ks[1] == 0);
  const int k = is64 ? ks[2 * ci]  : ks[ci];
  const int d = is64 ? dil[2 * ci] : dil[ci];
  const int p = is64 ? pad[2 * ci] : pad[ci];
  const int L = S_LEN + 2 * p - d * (k - 1);
  const int A = L / d, B = L - A * d;
  // cost: outputs + per-column priming + d==1 scalar penalty
  const int cost = L * (k + 7) + (d >> 1) * (k * 6) + ((d == 1) ? L * (k + 4) : 0);
  cost_s[ci] = cost;
  __syncthreads();
  int rank = 0;
  for (int j = 0; j < NCONV; ++j) {
    const int cj = cost_s[j];
    rank += (cj > cost) || (cj == cost && j < ci);
  }
  const int lvl = rank >> 3;          // 16 wave-levels
  int gg = rank & 7;                  // 8 groups
  if (lvl & 1) gg = 7 - gg;           // snake-deal -> balanced blocks
  int* dsc = ws + (gg * 16 + lvl) * DSTRIDE;
  dsc[0] = d; dsc[1] = p; dsc[2] = A; dsc[3] = B; dsc[4] = ci; dsc[7] = k;
  ((float*)dsc)[5] = 1.0f / (float)L;
  ((float*)dsc)[6] = bias[ci];
#pragma unroll
  for (int t = 0; t < 11; ++t) ((float*)dsc)[8 + t] = W[ci * 11 + t];
}

// ---------------- helpers ----------------
__device__ __forceinline__ float sgpr_f(float v) {
  return __int_as_float(__builtin_amdgcn_readfirstlane(__float_as_int(v)));
}
__device__ __forceinline__ int sgpr_i(int v) {
  return __builtin_amdgcn_readfirstlane(v);
}
__device__ __forceinline__ float rcpf(float x) { return __builtin_amdgcn_rcpf(x); }

// exact floor(num/d), num in [0, ~2^22), rd ~= 1/d; NO v_div sequences
__device__ __forceinline__ int divq(int num, float rd, int d) {
  int q = (int)((float)num * rd);
  q -= (q * d > num);
  q += ((q + 1) * d <= num);
  return q;
}

__device__ __forceinline__ float lds_at(const float* sh, int pos) {
  unsigned idx = (unsigned)pos;
  idx = idx > (unsigned)ZSLOT ? (unsigned)ZSLOT : idx;
  return sh[idx];
}

__device__ __forceinline__ f2 pfma(f2 a, f2 b, f2 c) {
#if __has_builtin(__builtin_elementwise_fma)
  return __builtin_elementwise_fma(a, b, c);
#else
  f2 r; r.x = fmaf(a.x, b.x, c.x); r.y = fmaf(a.y, b.y, c.y); return r;
#endif
}
__device__ __forceinline__ f2 pmax(f2 a, f2 b) {
#if __has_builtin(__builtin_elementwise_max)
  return __builtin_elementwise_max(a, b);
#else
  f2 r; r.x = fmaxf(a.x, b.x); r.y = fmaxf(a.y, b.y); return r;
#endif
}

// ---------------- scalar rotate walk (K=11 fixed; w zero-padded => exact).
// Used ONLY for d==1 convs and the odd-d remainder class. ----------------
template <bool SAFE, bool EXACT>
__device__ __forceinline__ void walk11s(
    const float* sh, const float* w, float bval,
    int d, int sb, int q0, int q1, float& mx, int& cnt)
{
  const int n = q1 - q0;
  if (n <= 0) return;
  float win[11];
  int pos = sb + q0 * d;
#pragma unroll
  for (int t = 0; t < 10; ++t) {
    win[t] = SAFE ? lds_at(sh, pos) : sh[pos];
    pos += d;
  }
  for (int i = 0; i < n; i += 11) {
#pragma unroll
    for (int s = 0; s < 11; ++s) {
      win[(s + 10) % 11] = SAFE ? lds_at(sh, pos) : sh[pos];
      pos += d;
      float a = bval;
#pragma unroll
      for (int t = 0; t < 11; ++t) a = fmaf(w[t], win[(s + t) % 11], a);
      if (EXACT || (i + s < n)) { mx = fmaxf(mx, a); cnt += (a >= 0.f); }
    }
  }
}

__device__ __forceinline__ void cls11(
    const float* sh, const float* w, float bval,
    int d, float rd, int p, int r, int q0, int q1, float& mx, int& cnt)
{
  if (q1 <= q0) return;
  const int qlo = (p > r) ? divq(p - r + d - 1, rd, d) : 0;
  const int qhi = divq(S_LEN - 1 - r + p, rd, d) - 10;
  int i0 = min(max(qlo, q0), q1);
  int i1 = min(qhi + 1, q1); if (i1 < i0) i1 = i0;
  const int nI = i1 - i0;
  const int nE = nI - nI % 11;
  walk11s<true,  false>(sh, w, bval, d, r - p, q0, i0, mx, cnt);
  walk11s<false, true >(sh, w, bval, d, r - p, i0, i0 + nE, mx, cnt);
  walk11s<true,  false>(sh, w, bval, d, r - p, i0 + nE, q1, mx, cnt);
}

// split class r's [0,Q) over 64 lanes with mod-32 stagger
__device__ __forceinline__ void scalar_split11(
    const float* sh, const float* w, float bval,
    int d, float rd, int p, int r, int Q, int lane, float& mx, int& cnt)
{
  if (Q <= 0) return;
  const int v  = lane;
  const int mm = Q >> 6;
  const int sA = (mm >= 32) ? (v & 31) : (((v & 31) * mm) >> 5);
  const int vB = v + 1;
  const int sB = (mm >= 32) ? (vB & 31) : (((vB & 31) * mm) >> 5);
  const int q0 = (int)(((long long)Q * v) >> 6) + sA;
  const int q1 = (v == 63) ? Q : (int)(((long long)Q * vB) >> 6) + sB;
  cls11(sh, w, bval, d, rd, p, r, q0, q1, mx, cnt);
}

// ---------------- boundary: one pair of outputs (classes r0, r0+1) at q,
// clamped loads; K-specific tap count ----------------
template <int K>
__device__ __forceinline__ void one_pair(
    const float* sh, const float* w, float bval,
    int d, int p, int r0, int q, float& mxs, int& ca, int& cb)
{
  int pos = r0 - p + q * d;
  float a0 = bval, a1 = bval;
#pragma unroll
  for (int t = 0; t < K; ++t) {
    a0 = fmaf(w[t], lds_at(sh, pos), a0);
    a1 = fmaf(w[t], lds_at(sh, pos + 1), a1);
    pos += d;
  }
  mxs = fmaxf(mxs, fmaxf(a0, a1));
  ca += (a0 >= 0.f); cb += (a1 >= 0.f);
}

// single dangling output of class r0 at q=A (Q0>Q1 case)
template <int K>
__device__ __forceinline__ void one_out(
    const float* sh, const float* w, float bval,
    int d, int p, int j, float& mx, int& cnt)
{
  float a = bval;
  int pos = j - p;
#pragma unroll
  for (int t = 0; t < K; ++t) { a = fmaf(w[t], lds_at(sh, pos), a); pos += d; }
  mx = fmaxf(mx, a);
  cnt += (a >= 0.f);
}

// ---------------- interior pair walk: EXACT (n % K == 0), RAW reads (bounds
// guaranteed by caller), no lookahead, merged accumulator ----------------
template <int K>
__device__ __forceinline__ void pwalk(
    const float* sh, const float* w, float bval,
    int d, int sb, int q0, int n, f2& mxv, int& ca, int& cb)
{
  if (n <= 0) return;
  f2 win[K];
  int pos = sb + q0 * d;
#pragma unroll
  for (int t = 0; t < K - 1; ++t) {
    f2 vv; vv.x = sh[pos]; vv.y = sh[pos + 1];
    win[t] = vv; pos += d;
  }
  for (int i = 0; i < n; i += K) {
#pragma unroll
    for (int s = 0; s < K; ++s) {
      f2 cur; cur.x = sh[pos]; cur.y = sh[pos + 1];
      pos += d;
      f2 a; a.x = bval; a.y = bval;
#pragma unroll
      for (int t = 0; t < K; ++t) {
        const f2 xv = (t == K - 1) ? cur : win[(s + t) % K];
        f2 wv; wv.x = w[t]; wv.y = w[t];
        a = pfma(wv, xv, a);
      }
      win[(s + K - 1) % K] = cur;
      mxv = pmax(mxv, a);
      ca += (a.x >= 0.f);
      cb += (a.y >= 0.f);
    }
  }
}

// pair column (r0, r0+1), q in [q0,q1): one_pair boundaries + exact interior
template <int K>
__device__ __forceinline__ void pc(
    const float* sh, const float* w, float bval,
    int d, float rd, int p, int r0, int q0, int q1,
    f2& mxv, float& mxs, int& ca, int& cb)
{
  if (q1 <= q0) return;
  const int qlo = (p > r0) ? divq(p - r0 + d - 1, rd, d) : 0;
  const int qhi = divq(S_LEN - 2 - r0 + p, rd, d) - (K - 1);
  int i0 = min(max(qlo, q0), q1);
  int i1 = min(qhi + 1, q1); if (i1 < i0) i1 = i0;
  int nE = i1 - i0; nE -= nE % K;
  for (int q = q0; q < i0; ++q)
    one_pair<K>(sh, w, bval, d, p, r0, q, mxs, ca, cb);
  pwalk<K>(sh, w, bval, d, r0 - p, i0, nE, mxv, ca, cb);
  for (int q = i0 + nE; q < q1; ++q)
    one_pair<K>(sh, w, bval, d, p, r0, q, mxs, ca, cb);
}

template <int K>
__device__ __forceinline__ void conv_wave(
    const float* sh, const float* w, float bval,
    int d, float rd, int p, int A, int B, int lane,
    f2& mxv, float& mxs, int& ca, int& cb)
{
  if (d == 1) {  // single class; stays scalar
    scalar_split11(sh, w, bval, 1, 1.0f, p, 0, A, lane, mxs, ca);
    return;
  }
  const int npair = d >> 1;
  if (npair >= 64) {
    // whole pair-columns per lane (adjacent lanes -> adjacent addresses)
    for (int g = lane; g < npair; g += 64) {
      const int r0 = 2 * g;
      const int Q0 = A + (r0 < B);        // = ceil((L-r)/d), 0 when r >= L
      const int Q1 = A + (r0 + 1 < B);
      pc<K>(sh, w, bval, d, rd, p, r0, 0, Q1, mxv, mxs, ca, cb);
      if (Q0 > Q1) one_out<K>(sh, w, bval, d, p, r0 + A * d, mxs, ca);
    }
  } else {
    // split each pair-column's q-range among its lanes (staggered)
    const float rdp = rcpf((float)npair);
    int v  = (int)((float)lane * rdp);
    int g2 = lane - v * npair;
    if (g2 < 0)           { --v; g2 += npair; }
    else if (g2 >= npair) { ++v; g2 -= npair; }
    const int nv = divq(63 - g2, rdp, npair) + 1;
    const int r0 = 2 * g2;
    const int Q0 = A + (r0 < B);
    const int Q1 = A + (r0 + 1 < B);
    const float rn = rcpf((float)nv);
    const int mm = (int)((float)Q1 * rn);
    const int sA = (mm >= 32) ? (v & 31) : (((v & 31) * mm) >> 5);
    const int vB = v + 1;
    const int sB = (mm >= 32) ? (vB & 31) : (((vB & 31) * mm) >> 5);
    const int q0 = (int)((float)(Q1 * v) * rn) + sA;       // v==0 -> 0
    const int q1 = (v == nv - 1) ? Q1 : (int)((float)(Q1 * vB) * rn) + sB;
    pc<K>(sh, w, bval, d, rd, p, r0, q0, q1, mxv, mxs, ca, cb);
    if (v == nv - 1 && Q0 > Q1)
      one_out<K>(sh, w, bval, d, p, r0 + A * d, mxs, ca);
  }
  if (d & 1)  // odd d: unpaired last class, split across all lanes
    scalar_split11(sh, w, bval, d, rd, p, d - 1, A + ((d - 1) < B), lane, mxs, ca);
}

// ---------------- hot kernel ----------------
__global__ __launch_bounds__(TPB, 8) void rocket_feats(
    const float* __restrict__ x, const int* __restrict__ ws,
    float* __restrict__ out)
{
  __shared__ float sh[S_LEN + 2];  // 64.5KB -> 2 blocks/CU, 32 waves/CU

  const int tid  = threadIdx.x;
  const int blk  = blockIdx.x;   // blk = b*8 + g: row's blocks dispatch-adjacent
  const int g    = blk & 7;
  const int b    = blk >> 3;
  const int lane = tid & 63, wid = tid >> 6;  // wid in [0,16)

  const float* xrow = x + (size_t)b * S_LEN;
  {
    const float* gb = xrow + lane * 4;
#pragma unroll
    for (int c = 0; c < 4; ++c) {
      const int off = (wid * 4 + c) * 256;  // floats
      __builtin_amdgcn_global_load_lds((const as1_float*)(gb + off),
                                       (as3_float*)(sh + off), 16, 0, 0);
    }
  }
  if (tid == 0) { sh[ZSLOT] = 0.f; sh[ZSLOT + 1] = 0.f; }

  // wave-uniform descriptor -> SGPRs (overlaps with staging)
  const int* dsc = ws + (g * 16 + wid) * DSTRIDE;
  const int d  = sgpr_i(dsc[0]);
  const int p  = sgpr_i(dsc[1]);
  const int A  = sgpr_i(dsc[2]);
  const int B  = sgpr_i(dsc[3]);
  const int ci = sgpr_i(dsc[4]);
  const int k  = sgpr_i(dsc[7]);
  const float invL = sgpr_f(((const float*)dsc)[5]);
  const float bval = sgpr_f(((const float*)dsc)[6]);
  float w[11];
#pragma unroll
  for (int t = 0; t < 11; ++t) w[t] = sgpr_f(((const float*)dsc)[8 + t]);

  __syncthreads();  // only barrier

  const float rd = rcpf((float)d);
  f2 mxv; mxv.x = -INFINITY; mxv.y = -INFINITY;
  float mxs = -INFINITY;
  int ca = 0, cb = 0;

  if (k == 7)      conv_wave<7 >(sh, w, bval, d, rd, p, A, B, lane, mxv, mxs, ca, cb);
  else if (k == 9) conv_wave<9 >(sh, w, bval, d, rd, p, A, B, lane, mxv, mxs, ca, cb);
  else             conv_wave<11>(sh, w, bval, d, rd, p, A, B, lane, mxv, mxs, ca, cb);

  float mx = fmaxf(fmaxf(mxv.x, mxv.y), mxs);
  int cnt = ca + cb;
#pragma unroll
  for (int off = 32; off > 0; off >>= 1) {
    mx = fmaxf(mx, __shfl_down(mx, off, 64));
    cnt += __shfl_down(cnt, off, 64);
  }
  if (lane == 0) {
    out[(size_t)b * (2 * NCONV) + 2 * ci]     = mx;
    out[(size_t)b * (2 * NCONV) + 2 * ci + 1] = (float)cnt * invL;
  }
}

extern "C" void kernel_launch(void* const* d_in, const int* in_sizes, int n_in,
                              void* d_out, int out_size, void* d_ws, size_t ws_size,
                              hipStream_t stream) {
  const float* x    = (const float*)d_in[0];
  const float* W    = (const float*)d_in[1];
  const float* bias = (const float*)d_in[2];
  const int*   ks   = (const int*)d_in[3];
  const int*   dil  = (const int*)d_in[4];
  const int*   pad  = (const int*)d_in[5];
  float* out = (float*)d_out;
  int*   ws  = (int*)d_ws;  // 128*20*4 = 10240 bytes

  hipLaunchKernelGGL(setup_desc, dim3(1), dim3(NCONV), 0, stream,
                     ks, dil, pad, W, bias, ws);
  hipLaunchKernelGGL(rocket_feats, dim3(NBATCH * NGRP), dim3(TPB), 0, stream,
                     x, ws, out);
}

// Round 11
// 297.594 us; speedup vs baseline: 1.5870x; 1.1514x over previous
//
#include <hip/hip_runtime.h>
#include <math.h>

#define S_LEN   16384
#define NCONV   128
#define NBATCH  256
#define TPB     1024   // 16 waves; 2 chunk work-items per wave
#define NGRP    8      // conv groups per row (16 convs, 32 chunks each)
#define ZSLOT   16384  // sh[ZSLOT]=sh[ZSLOT+1]=0: every OOB tap clamps here
#define DSTRIDE 24
#define BIGQ    (1 << 28)

typedef float __attribute__((address_space(1))) as1_float;
typedef float __attribute__((address_space(3))) as3_float;
typedef __attribute__((ext_vector_type(2))) float f2;
typedef unsigned long long u64;

// ---------------- setup: per-CHUNK descriptors, LPT fold balancing ----------
__global__ void setup_desc(const int* __restrict__ ks, const int* __restrict__ dil,
                           const int* __restrict__ pad, const float* __restrict__ W,
                           const float* __restrict__ bias, int* __restrict__ ws)
{
  __shared__ int cost_s[NCONV];
  __shared__ int grp_s[NCONV];
  const int ci = threadIdx.x;  // blockDim == 128
  const int is64 = (ks[1] == 0);
  const int k = is64 ? ks[2 * ci]  : ks[ci];
  const int d = is64 ? dil[2 * ci] : dil[ci];
  const int p = is64 ? pad[2 * ci] : pad[ci];
  const int L = S_LEN + 2 * p - d * (k - 1);
  const int A = L / d, B = L - A * d;
  int cost = L * (k + 9) + d * k * 3;
  if (d == 1) cost += L * (k + 9);     // scalar path ~2x slots/output
  cost_s[ci] = cost;
  __syncthreads();
  int rank = 0;
  for (int j = 0; j < NCONV; ++j) {
    const int cj = cost_s[j];
    rank += (cj > cost) || (cj == cost && j < ci);
  }
  int gg = rank & 7;
  if ((rank >> 3) & 1) gg = 7 - gg;    // snake-deal convs -> 8 balanced groups
  grp_s[ci] = gg;
  __syncthreads();
  int rho = 0;                         // in-group rank (descending cost)
  for (int j = 0; j < NCONV; ++j) {
    if (grp_s[j] != gg) continue;
    const int cj = cost_s[j];
    rho += (cj > cost) || (cj == cost && j < ci);
  }
  // 2 chunks per conv; fold: chunk j2=2*rho+h -> wave (j2<16 ? j2 : 31-j2).
  // Wave w gets chunk ranks w and 31-w -> big+small pairing, flat wave times.
#pragma unroll
  for (int h = 0; h < 2; ++h) {
    const int j2 = 2 * rho + h;
    const int wv = (j2 < 16) ? j2 : 31 - j2;
    const int sq = (j2 < 16) ? 0 : 1;
    int* dsc = ws + (gg * 32 + wv * 2 + sq) * DSTRIDE;
    dsc[0] = d; dsc[1] = p; dsc[2] = A; dsc[3] = B;
    dsc[4] = ci; dsc[5] = rho; dsc[6] = h; dsc[7] = k;
    ((float*)dsc)[8] = 1.0f / (float)L;
    ((float*)dsc)[9] = bias[ci];
#pragma unroll
    for (int t = 0; t < 11; ++t) ((float*)dsc)[10 + t] = W[ci * 11 + t];
  }
}

// ---------------- helpers ----------------
__device__ __forceinline__ float sgpr_f(float v) {
  return __int_as_float(__builtin_amdgcn_readfirstlane(__float_as_int(v)));
}
__device__ __forceinline__ int sgpr_i(int v) {
  return __builtin_amdgcn_readfirstlane(v);
}
__device__ __forceinline__ float rcpf(float x) { return __builtin_amdgcn_rcpf(x); }

// exact floor(num/d) for small non-negative num; no div sequences
__device__ __forceinline__ int divq(int num, float rd, int d) {
  int q = (int)((float)num * rd);
  q -= (q * d > num);
  q += ((q + 1) * d <= num);
  return q;
}

__device__ __forceinline__ float lds_at(const float* sh, int pos) {
  unsigned idx = (unsigned)pos;
  idx = idx > (unsigned)ZSLOT ? (unsigned)ZSLOT : idx;
  return sh[idx];
}
// clamped PAIR read: classes (r0,r0+1) -> (idx, idx+1); if r1's tap lands at
// 16384 it must be 0 (OOB) = sh[ZSLOT]; pos<0/huge -> (0,0). One v_min total.
__device__ __forceinline__ f2 rd2(const float* sh, int pos) {
  unsigned idx = (unsigned)pos;
  idx = idx > (unsigned)ZSLOT ? (unsigned)ZSLOT : idx;
  f2 v; v.x = sh[idx]; v.y = sh[idx + 1];
  return v;
}

__device__ __forceinline__ f2 pfma(f2 a, f2 b, f2 c) {
#if __has_builtin(__builtin_elementwise_fma)
  return __builtin_elementwise_fma(a, b, c);
#else
  f2 r; r.x = fmaf(a.x, b.x, c.x); r.y = fmaf(a.y, b.y, c.y); return r;
#endif
}
__device__ __forceinline__ f2 pmax(f2 a, f2 b) {
#if __has_builtin(__builtin_elementwise_max)
  return __builtin_elementwise_max(a, b);
#else
  f2 r; r.x = fmaxf(a.x, b.x); r.y = fmaxf(a.y, b.y); return r;
#endif
}

// ---------------- pair walk: ALL reads clamped (no interior/boundary split),
// weights as wave-uniform u64 (both halves = w[t]) -> SGPR-pair VOP3P source,
// zero weight-broadcast movs. Guarded K-1 tail reuses the window. ----------
template <int K>
__device__ __forceinline__ void pwalk(
    const float* sh, const u64* wu, float bval,
    int d, int sb, int q0, int q1, f2& mxv, int& ca, int& cb)
{
  const int n = q1 - q0;
  if (n <= 0) return;
  f2 win[K];
  int pos = sb + q0 * d;
#pragma unroll
  for (int t = 0; t < K - 1; ++t) { win[t] = rd2(sh, pos); pos += d; }
  f2 bb; bb.x = bval; bb.y = bval;
  int i = 0;
  for (; i + K <= n; i += K) {
#pragma unroll
    for (int s = 0; s < K; ++s) {
      const f2 cur = rd2(sh, pos); pos += d;
      f2 a = bb;
#pragma unroll
      for (int t = 0; t < K; ++t) {
        const f2 wv = __builtin_bit_cast(f2, wu[t]);
        a = pfma(wv, (t == K - 1) ? cur : win[(s + t) % K], a);
      }
      win[(s + K - 1) % K] = cur;
      mxv = pmax(mxv, a);
      ca += (a.x >= 0.f); cb += (a.y >= 0.f);
    }
  }
  const int rem = n - i;
  if (rem > 0) {
#pragma unroll
    for (int s = 0; s < K - 1; ++s) {
      const f2 cur = rd2(sh, pos); pos += d;
      f2 a = bb;
#pragma unroll
      for (int t = 0; t < K; ++t) {
        const f2 wv = __builtin_bit_cast(f2, wu[t]);
        a = pfma(wv, (t == K - 1) ? cur : win[(s + t) % K], a);
      }
      win[(s + K - 1) % K] = cur;
      if (s < rem) { mxv = pmax(mxv, a); ca += (a.x >= 0.f); cb += (a.y >= 0.f); }
    }
  }
}

// ---------------- scalar rotate walk (11 taps, w zero-padded), clamped ------
__device__ __forceinline__ void swalk(
    const float* sh, const float* w, float bval,
    int d, int sb, int q0, int q1, float& mx, int& cnt)
{
  const int n = q1 - q0;
  if (n <= 0) return;
  float win[11];
  int pos = sb + q0 * d;
#pragma unroll
  for (int t = 0; t < 10; ++t) { win[t] = lds_at(sh, pos); pos += d; }
  int i = 0;
  for (; i + 11 <= n; i += 11) {
#pragma unroll
    for (int s = 0; s < 11; ++s) {
      win[(s + 10) % 11] = lds_at(sh, pos); pos += d;
      float a = bval;
#pragma unroll
      for (int t = 0; t < 11; ++t) a = fmaf(w[t], win[(s + t) % 11], a);
      mx = fmaxf(mx, a); cnt += (a >= 0.f);
    }
  }
  const int rem = n - i;
  if (rem > 0) {
#pragma unroll
    for (int s = 0; s < 10; ++s) {
      win[(s + 10) % 11] = lds_at(sh, pos); pos += d;
      float a = bval;
#pragma unroll
      for (int t = 0; t < 11; ++t) a = fmaf(w[t], win[(s + t) % 11], a);
      if (s < rem) { mx = fmaxf(mx, a); cnt += (a >= 0.f); }
    }
  }
}

// split class r's q-range [c0,c1) over 64 lanes with mod-32 stagger
__device__ __forceinline__ void scalar_split(
    const float* sh, const float* w, float bval,
    int d, int p, int r, int c0, int c1, int lane, float& mx, int& cnt)
{
  const int n = c1 - c0;
  if (n <= 0) return;
  const int v  = lane;
  const int mm = n >> 6;
  const int sA = (mm >= 32) ? (v & 31) : (((v & 31) * mm) >> 5);
  const int vB = v + 1;
  const int sB = (mm >= 32) ? (vB & 31) : (((vB & 31) * mm) >> 5);
  const int q0 = c0 + (int)(((long long)n * v) >> 6) + sA;
  const int q1 = (v == 63) ? c1 : c0 + (int)(((long long)n * vB) >> 6) + sB;
  swalk(sh, w, bval, d, r - p, q0, q1, mx, cnt);
}

template <int K>
__device__ __forceinline__ void one_out(
    const float* sh, const float* w, float bval,
    int d, int p, int j, float& mx, int& cnt)
{
  float a = bval;
  int pos = j - p;
#pragma unroll
  for (int t = 0; t < K; ++t) { a = fmaf(w[t], lds_at(sh, pos), a); pos += d; }
  mx = fmaxf(mx, a); cnt += (a >= 0.f);
}

// ---------------- one chunk of one conv ----------------
template <int K>
__device__ __forceinline__ void conv_chunk(
    const float* sh, const u64* wu, const float* w, float bval,
    int d, int p, int A, int B, int h, int lane,
    f2& mxv, float& mxs, int& ca, int& cb)
{
  if (d == 1) {                      // single class (A == L), scalar q-split
    const int H = (A + 1) >> 1;
    scalar_split(sh, w, bval, 1, p, 0, h ? H : 0, h ? A : H, lane, mxs, ca);
    return;
  }
  const int npair = d >> 1;
  if (npair >= 128) {
    // COLUMN-split: chunk h owns a contiguous half of the pair-columns
    const int half = npair >> 1;
    const int g0 = h ? half : 0;
    const int g1 = h ? npair : half;
    for (int c = g0 + lane; c < g1; c += 64) {
      const int r0 = 2 * c;
      const int Qm = A + (r0 + 1 < B);
      pwalk<K>(sh, wu, bval, d, r0 - p, 0, Qm, mxv, ca, cb);
      if (B == r0 + 1) one_out<K>(sh, w, bval, d, p, r0 + A * d, mxs, ca);
    }
  } else if (npair >= 64) {
    // whole columns per lane, q-split [c0,c1)
    const int H = (A + 1) >> 1;
    const int c0 = h ? H : 0;
    const int c1 = h ? BIGQ : H;
    for (int c = lane; c < npair; c += 64) {
      const int r0 = 2 * c;
      const int Qm = A + (r0 + 1 < B);
      pwalk<K>(sh, wu, bval, d, r0 - p, c0, min(c1, Qm), mxv, ca, cb);
      if (B == r0 + 1 && A >= c0 && A < c1)
        one_out<K>(sh, w, bval, d, p, r0 + A * d, mxs, ca);
    }
  } else {
    // lane-compose (nv lanes per column), q-split [c0,c1)
    const int H = (A + 1) >> 1;
    const int c0 = h ? H : 0;
    const int c1h = h ? BIGQ : H;
    const float rdp = rcpf((float)npair);
    int v  = (int)((float)lane * rdp);
    int g2 = lane - v * npair;
    if (g2 < 0)           { --v; g2 += npair; }
    else if (g2 >= npair) { ++v; g2 -= npair; }
    const int nv = divq(63 - g2, rdp, npair) + 1;
    const int r0 = 2 * g2;
    const int Qm = A + (r0 + 1 < B);
    const int cc1 = min(c1h, Qm);
    const int n = cc1 - c0;
    if (n > 0) {
      const float rn = rcpf((float)nv);
      const int mm = (int)((float)n * rn);
      const int sA = (mm >= 32) ? (v & 31) : (((v & 31) * mm) >> 5);
      const int vB = v + 1;
      const int sB = (mm >= 32) ? (vB & 31) : (((vB & 31) * mm) >> 5);
      const int q0 = c0 + (int)((float)(n * v) * rn) + sA;   // v==0 -> c0
      const int q1 = (v == nv - 1) ? cc1
                   : c0 + (int)((float)(n * vB) * rn) + sB;
      pwalk<K>(sh, wu, bval, d, r0 - p, q0, q1, mxv, ca, cb);
    }
    if (v == nv - 1 && B == r0 + 1 && A >= c0 && A < c1h)
      one_out<K>(sh, w, bval, d, p, r0 + A * d, mxs, ca);
  }
  if ((d & 1) && d > 1) {            // odd d: unpaired last class, q-split
    const int H2 = (A + 1) >> 1;
    const int r = d - 1;
    const int Qr = A + (r < B);
    const int c0 = h ? H2 : 0;
    const int c1 = h ? Qr : min(H2, Qr);
    scalar_split(sh, w, bval, d, p, r, c0, c1, lane, mxs, ca);
  }
}

// ---------------- hot kernel ----------------
__global__ __launch_bounds__(TPB, 8) void rocket_feats(
    const float* __restrict__ x, const int* __restrict__ ws,
    float* __restrict__ out)
{
  __shared__ float sh[S_LEN + 2];    // 64.5KB -> 2 blocks/CU, 32 waves/CU
  __shared__ float smx[2][16];
  __shared__ int   scn[2][16];
  __shared__ int   sci[16];
  __shared__ float sin_[16];

  const int tid  = threadIdx.x;
  const int blk  = blockIdx.x;       // blk = b*8 + g: row's blocks adjacent
  const int g    = blk & 7;
  const int b    = blk >> 3;
  const int lane = tid & 63, wid = tid >> 6;   // wid in [0,16)

  const float* xrow = x + (size_t)b * S_LEN;
  {
    const float* gb = xrow + lane * 4;
#pragma unroll
    for (int c = 0; c < 4; ++c) {
      const int off = (wid * 4 + c) * 256;  // floats
      __builtin_amdgcn_global_load_lds((const as1_float*)(gb + off),
                                       (as3_float*)(sh + off), 16, 0, 0);
    }
  }
  if (tid == 0) { sh[ZSLOT] = 0.f; sh[ZSLOT + 1] = 0.f; }
  __syncthreads();

  for (int sq = 0; sq < 2; ++sq) {
    const int* dsc = ws + (g * 32 + wid * 2 + sq) * DSTRIDE;
    const int d  = sgpr_i(dsc[0]);
    const int p  = sgpr_i(dsc[1]);
    const int A  = sgpr_i(dsc[2]);
    const int B  = sgpr_i(dsc[3]);
    const int ci = sgpr_i(dsc[4]);
    const int t_ = sgpr_i(dsc[5]);
    const int h  = sgpr_i(dsc[6]);
    const int k  = sgpr_i(dsc[7]);
    const float invL = sgpr_f(((const float*)dsc)[8]);
    const float bval = sgpr_f(((const float*)dsc)[9]);
    float wf[11]; u64 wu[11];
#pragma unroll
    for (int t = 0; t < 11; ++t) {
      wf[t] = sgpr_f(((const float*)dsc)[10 + t]);
      const unsigned wb = (unsigned)__float_as_int(wf[t]);
      wu[t] = ((u64)wb << 32) | (u64)wb;   // wave-uniform -> SGPR pair
    }

    f2 mxv; mxv.x = -INFINITY; mxv.y = -INFINITY;
    float mxs = -INFINITY;
    int ca = 0, cb = 0;

    if (k == 7)
      conv_chunk<7 >(sh, wu, wf, bval, d, p, A, B, h, lane, mxv, mxs, ca, cb);
    else if (k == 9)
      conv_chunk<9 >(sh, wu, wf, bval, d, p, A, B, h, lane, mxv, mxs, ca, cb);
    else
      conv_chunk<11>(sh, wu, wf, bval, d, p, A, B, h, lane, mxv, mxs, ca, cb);

    float mx = fmaxf(fmaxf(mxv.x, mxv.y), mxs);
    int cnt = ca + cb;
#pragma unroll
    for (int off = 32; off > 0; off >>= 1) {
      mx = fmaxf(mx, __shfl_down(mx, off, 64));
      cnt += __shfl_down(cnt, off, 64);
    }
    if (lane == 0) {
      smx[h][t_] = mx; scn[h][t_] = cnt;
      sci[t_] = ci; sin_[t_] = invL;       // same value from both chunks
    }
  }

  __syncthreads();
  if (tid < 16) {
    const float m = fmaxf(smx[0][tid], smx[1][tid]);
    const int   c = scn[0][tid] + scn[1][tid];
    out[(size_t)b * (2 * NCONV) + 2 * sci[tid]]     = m;
    out[(size_t)b * (2 * NCONV) + 2 * sci[tid] + 1] = (float)c * sin_[tid];
  }
}

extern "C" void kernel_launch(void* const* d_in, const int* in_sizes, int n_in,
                              void* d_out, int out_size, void* d_ws, size_t ws_size,
                              hipStream_t stream) {
  const float* x    = (const float*)d_in[0];
  const float* W    = (const float*)d_in[1];
  const float* bias = (const float*)d_in[2];
  const int*   ks   = (const int*)d_in[3];
  const int*   dil  = (const int*)d_in[4];
  const int*   pad  = (const int*)d_in[5];
  float* out = (float*)d_out;
  int*   ws  = (int*)d_ws;  // 8*32*24*4 = 24576 bytes

  hipLaunchKernelGGL(setup_desc, dim3(1), dim3(NCONV), 0, stream,
                     ks, dil, pad, W, bias, ws);
  hipLaunchKernelGGL(rocket_feats, dim3(NBATCH * NGRP), dim3(TPB), 0, stream,
                     x, ws, out);
}

// Round 12
// 270.771 us; speedup vs baseline: 1.7442x; 1.0991x over previous
//
#include <hip/hip_runtime.h>
#include <math.h>

#define S_LEN   16384
#define NCONV   128
#define NBATCH  256
#define TPB     1024   // 16 waves; 2 chunk work-items per wave
#define NGRP    8      // conv groups per row (16 convs, 32 chunks each)
#define DSTRIDE 24
#define BIGQ    (1 << 28)
// LDS layout: sh[0..3]=0 | sh[4+i]=x[i] (i<16384) | sh[16388..16389]=0
// Clamped index (bytes): min(unsigned((4+pos)*4), 65552). pos=-1 -> (0, x[0]).
#define CLMP    65552u

typedef float __attribute__((address_space(1))) as1_float;
typedef float __attribute__((address_space(3))) as3_float;
typedef __attribute__((ext_vector_type(2))) float f2;
typedef unsigned long long u64;

// ---------------- setup: per-CHUNK descriptors, LPT fold balancing ----------
__global__ void setup_desc(const int* __restrict__ ks, const int* __restrict__ dil,
                           const int* __restrict__ pad, const float* __restrict__ W,
                           const float* __restrict__ bias, int* __restrict__ ws)
{
  __shared__ int cost_s[NCONV];
  __shared__ int grp_s[NCONV];
  const int ci = threadIdx.x;  // blockDim == 128
  const int is64 = (ks[1] == 0);
  const int k = is64 ? ks[2 * ci]  : ks[ci];
  const int d = is64 ? dil[2 * ci] : dil[ci];
  const int p = is64 ? pad[2 * ci] : pad[ci];
  const int L = S_LEN + 2 * p - d * (k - 1);
  const int A = L / d, B = L - A * d;
  int cost = L * (k + 5) + ((d >= 128) ? (d >> 1) : 64) * (k - 1) * 2;
  if (d == 1) cost = L * (k + 5) * 2;   // scalar path ~2x slots/output
  cost_s[ci] = cost;
  __syncthreads();
  int rank = 0;
  for (int j = 0; j < NCONV; ++j) {
    const int cj = cost_s[j];
    rank += (cj > cost) || (cj == cost && j < ci);
  }
  int gg = rank & 7;
  if ((rank >> 3) & 1) gg = 7 - gg;    // snake-deal convs -> 8 balanced groups
  grp_s[ci] = gg;
  __syncthreads();
  int rho = 0;                         // in-group rank (descending cost)
  for (int j = 0; j < NCONV; ++j) {
    if (grp_s[j] != gg) continue;
    const int cj = cost_s[j];
    rho += (cj > cost) || (cj == cost && j < ci);
  }
  // 2 chunks per conv; fold: chunk j2=2*rho+h -> wave (j2<16 ? j2 : 31-j2).
#pragma unroll
  for (int h = 0; h < 2; ++h) {
    const int j2 = 2 * rho + h;
    const int wv = (j2 < 16) ? j2 : 31 - j2;
    const int sq = (j2 < 16) ? 0 : 1;
    int* dsc = ws + (gg * 32 + wv * 2 + sq) * DSTRIDE;
    dsc[0] = d; dsc[1] = p; dsc[2] = A; dsc[3] = B;
    dsc[4] = ci; dsc[5] = rho; dsc[6] = h; dsc[7] = k;
    ((float*)dsc)[8] = 1.0f / (float)L;
    ((float*)dsc)[9] = bias[ci];
#pragma unroll
    for (int t = 0; t < 11; ++t) ((float*)dsc)[10 + t] = W[ci * 11 + t];
  }
}

// ---------------- helpers ----------------
__device__ __forceinline__ float sgpr_f(float v) {
  return __int_as_float(__builtin_amdgcn_readfirstlane(__float_as_int(v)));
}
__device__ __forceinline__ int sgpr_i(int v) {
  return __builtin_amdgcn_readfirstlane(v);
}
__device__ __forceinline__ float rcpf(float x) { return __builtin_amdgcn_rcpf(x); }

// exact floor(num/d) for small non-negative num; no div sequences
__device__ __forceinline__ int divq(int num, float rd, int d) {
  int q = (int)((float)num * rd);
  q -= (q * d > num);
  q += ((q + 1) * d <= num);
  return q;
}

// byte-indexed clamped reads against the shifted layout
__device__ __forceinline__ f2 rd2b(const float* sh, int ib) {
  unsigned u = (unsigned)ib;
  u = u > CLMP ? CLMP : u;                       // one v_min_u32
  const float* p = (const float*)((const char*)sh + u);
  f2 v; v.x = p[0]; v.y = p[1];                  // fused ds_read2_b32
  return v;
}
__device__ __forceinline__ float ld1b(const float* sh, int ib) {
  unsigned u = (unsigned)ib;
  u = u > CLMP ? CLMP : u;
  return *(const float*)((const char*)sh + u);
}

__device__ __forceinline__ f2 pfma(f2 a, f2 b, f2 c) {
#if __has_builtin(__builtin_elementwise_fma)
  return __builtin_elementwise_fma(a, b, c);
#else
  f2 r; r.x = fmaf(a.x, b.x, c.x); r.y = fmaf(a.y, b.y, c.y); return r;
#endif
}
__device__ __forceinline__ f2 pmax(f2 a, f2 b) {
#if __has_builtin(__builtin_elementwise_max)
  return __builtin_elementwise_max(a, b);
#else
  f2 r; r.x = fmaxf(a.x, b.x); r.y = fmaxf(a.y, b.y); return r;
#endif
}
__device__ __forceinline__ int wcount(bool pred) {   // wave-total, SALU adds
  return (int)__popcll(__ballot(pred));
}

// ---------------- interior pair walk: classes (r0, r0+1), all reads clamped
// (correct everywhere incl. pos=-1 via shifted layout), weights as SGPR-pair
// u64, bias folded into tap-0 pfma, SALU-hoisted s*d addressing, ballot cnt.
template <int K>
__device__ __forceinline__ void pwalk(
    const float* sh, const u64* wu, const f2 bbv,
    int d, int sb4, int q0, int q1, f2& mxv, int& cw)
{
  const int n = q1 - q0;
  if (n <= 0) return;
  f2 win[K];
  int bb = (sb4 + q0 * d) * 4;                 // byte index
#pragma unroll
  for (int t = 0; t < K - 1; ++t)
    win[t] = rd2b(sh, bb + t * (d * 4));       // t*(d*4): SALU, hoisted
  bb += (K - 1) * (d * 4);
  int i = 0;
  for (; i + K <= n; i += K) {
#pragma unroll
    for (int s = 0; s < K; ++s) {
      const f2 cur = rd2b(sh, bb + s * (d * 4));
      f2 a = pfma(__builtin_bit_cast(f2, wu[0]), win[s % K], bbv);
#pragma unroll
      for (int t = 1; t < K; ++t)
        a = pfma(__builtin_bit_cast(f2, wu[t]),
                 (t == K - 1) ? cur : win[(s + t) % K], a);
      win[(s + K - 1) % K] = cur;
      mxv = pmax(mxv, a);
      cw += wcount(a.x >= 0.f);
      cw += wcount(a.y >= 0.f);
    }
    bb += K * (d * 4);
  }
  const int rem = n - i;
  if (rem > 0) {
#pragma unroll
    for (int s = 0; s < K - 1; ++s) {
      const f2 cur = rd2b(sh, bb + s * (d * 4));
      f2 a = pfma(__builtin_bit_cast(f2, wu[0]), win[s % K], bbv);
#pragma unroll
      for (int t = 1; t < K; ++t)
        a = pfma(__builtin_bit_cast(f2, wu[t]),
                 (t == K - 1) ? cur : win[(s + t) % K], a);
      win[(s + K - 1) % K] = cur;
      const bool ok = (s < rem);
      if (ok) mxv = pmax(mxv, a);
      cw += wcount(ok && (a.x >= 0.f));
      cw += wcount(ok && (a.y >= 0.f));
    }
  }
}

// ---------------- scalar rotate walk (d==1 convs, odd-d remainder class) ----
template <int K>
__device__ __forceinline__ void swalk(
    const float* sh, const float* w, float bval,
    int d, int sb4, int q0, int q1, float& mx, int& cw)
{
  const int n = q1 - q0;
  if (n <= 0) return;
  float win[K];
  int bb = (sb4 + q0 * d) * 4;
#pragma unroll
  for (int t = 0; t < K - 1; ++t)
    win[t] = ld1b(sh, bb + t * (d * 4));
  bb += (K - 1) * (d * 4);
  int i = 0;
  for (; i + K <= n; i += K) {
#pragma unroll
    for (int s = 0; s < K; ++s) {
      const float cur = ld1b(sh, bb + s * (d * 4));
      float a = fmaf(w[0], win[s % K], bval);
#pragma unroll
      for (int t = 1; t < K; ++t)
        a = fmaf(w[t], (t == K - 1) ? cur : win[(s + t) % K], a);
      win[(s + K - 1) % K] = cur;
      mx = fmaxf(mx, a);
      cw += wcount(a >= 0.f);
    }
    bb += K * (d * 4);
  }
  const int rem = n - i;
  if (rem > 0) {
#pragma unroll
    for (int s = 0; s < K - 1; ++s) {
      const float cur = ld1b(sh, bb + s * (d * 4));
      float a = fmaf(w[0], win[s % K], bval);
#pragma unroll
      for (int t = 1; t < K; ++t)
        a = fmaf(w[t], (t == K - 1) ? cur : win[(s + t) % K], a);
      win[(s + K - 1) % K] = cur;
      const bool ok = (s < rem);
      if (ok) mx = fmaxf(mx, a);
      cw += wcount(ok && (a >= 0.f));
    }
  }
}

// split class r's q-range [c0,c1) over 64 lanes with mod-32 stagger
template <int K>
__device__ __forceinline__ void scalar_split(
    const float* sh, const float* w, float bval,
    int d, int p, int r, int c0, int c1, int lane, float& mx, int& cw)
{
  const int n = c1 - c0;
  if (n <= 0) return;
  const int v  = lane;
  const int mm = n >> 6;
  const int sA = (mm >= 32) ? (v & 31) : (((v & 31) * mm) >> 5);
  const int vB = v + 1;
  const int sB = (mm >= 32) ? (vB & 31) : (((vB & 31) * mm) >> 5);
  const int q0 = c0 + (int)(((long long)n * v) >> 6) + sA;
  const int q1 = (v == 63) ? c1 : c0 + (int)(((long long)n * vB) >> 6) + sB;
  swalk<K>(sh, w, bval, d, r - p + 4, q0, q1, mx, cw);
}

template <int K>
__device__ __forceinline__ void one_out(
    const float* sh, const float* w, float bval,
    int d, int p, int j, float& mx, int& cw)
{
  float a = bval;
  int bb = (j - p + 4) * 4;
#pragma unroll
  for (int t = 0; t < K; ++t) { a = fmaf(w[t], ld1b(sh, bb), a); bb += d * 4; }
  mx = fmaxf(mx, a);
  cw += wcount(a >= 0.f);
}

// ---------------- one chunk of one conv ----------------
template <int K>
__device__ __forceinline__ void conv_chunk(
    const float* sh, const u64* wu, const float* w, float bval, const f2 bbv,
    int d, int p, int A, int B, int h, int lane,
    f2& mxv, float& mxs, int& cw)
{
  if (d == 1) {                      // single class (A == L), scalar q-split
    const int H = (A + 1) >> 1;
    scalar_split<K>(sh, w, bval, 1, p, 0, h ? H : 0, h ? A : H, lane, mxs, cw);
    return;
  }
  const int npair = d >> 1;
  if (npair >= 128) {
    // COLUMN-split: chunk h owns a contiguous half of the pair-columns
    const int half = npair >> 1;
    const int g0 = h ? half : 0;
    const int g1 = h ? npair : half;
    for (int c = g0 + lane; c < g1; c += 64) {
      const int r0 = 2 * c;
      const int Qm = A + (r0 + 1 < B);
      pwalk<K>(sh, wu, bbv, d, r0 - p + 4, 0, Qm, mxv, cw);
      if (B == r0 + 1) one_out<K>(sh, w, bval, d, p, r0 + A * d, mxs, cw);
    }
  } else if (npair >= 64) {
    // whole columns per lane, q-split [c0,c1)
    const int H = (A + 1) >> 1;
    const int c0 = h ? H : 0;
    const int c1 = h ? BIGQ : H;
    for (int c = lane; c < npair; c += 64) {
      const int r0 = 2 * c;
      const int Qm = A + (r0 + 1 < B);
      pwalk<K>(sh, wu, bbv, d, r0 - p + 4, c0, min(c1, Qm), mxv, cw);
      if (B == r0 + 1 && A >= c0 && A < c1)
        one_out<K>(sh, w, bval, d, p, r0 + A * d, mxs, cw);
    }
  } else {
    // lane-compose (nv lanes per column), q-split [c0,c1)
    const int H = (A + 1) >> 1;
    const int c0 = h ? H : 0;
    const int c1h = h ? BIGQ : H;
    const float rdp = rcpf((float)npair);
    int v  = (int)((float)lane * rdp);
    int g2 = lane - v * npair;
    if (g2 < 0)           { --v; g2 += npair; }
    else if (g2 >= npair) { ++v; g2 -= npair; }
    const int nv = divq(63 - g2, rdp, npair) + 1;
    const int r0 = 2 * g2;
    const int Qm = A + (r0 + 1 < B);
    const int cc1 = min(c1h, Qm);
    const int n = cc1 - c0;
    if (n > 0) {
      const float rn = rcpf((float)nv);
      const int mm = (int)((float)n * rn);
      const int sA = (mm >= 32) ? (v & 31) : (((v & 31) * mm) >> 5);
      const int vB = v + 1;
      const int sB = (mm >= 32) ? (vB & 31) : (((vB & 31) * mm) >> 5);
      const int q0 = c0 + (int)((float)(n * v) * rn) + sA;   // v==0 -> c0
      const int q1 = (v == nv - 1) ? cc1
                   : c0 + (int)((float)(n * vB) * rn) + sB;
      pwalk<K>(sh, wu, bbv, d, r0 - p + 4, q0, q1, mxv, cw);
    }
    if (v == nv - 1 && B == r0 + 1 && A >= c0 && A < c1h)
      one_out<K>(sh, w, bval, d, p, r0 + A * d, mxs, cw);
  }
  if ((d & 1) && d > 1) {            // odd d: unpaired last class, q-split
    const int H2 = (A + 1) >> 1;
    const int r = d - 1;
    const int Qr = A + (r < B);
    const int c0 = h ? H2 : 0;
    const int c1 = h ? Qr : min(H2, Qr);
    scalar_split<K>(sh, w, bval, d, p, r, c0, c1, lane, mxs, cw);
  }
}

// ---------------- hot kernel ----------------
__global__ __launch_bounds__(TPB, 8) void rocket_feats(
    const float* __restrict__ x, const int* __restrict__ ws,
    float* __restrict__ out)
{
  __shared__ float sh[S_LEN + 8];    // shifted layout; 2 blocks/CU
  __shared__ float smx[2][16];
  __shared__ int   scn[2][16];
  __shared__ int   sci[16];
  __shared__ float sin_[16];

  const int tid  = threadIdx.x;
  const int blk  = blockIdx.x;       // blk = b*8 + g: row's blocks adjacent
  const int g    = blk & 7;
  const int b    = blk >> 3;
  const int lane = tid & 63, wid = tid >> 6;   // wid in [0,16)

  const float* xrow = x + (size_t)b * S_LEN;
  {
    const float* gb = xrow + lane * 4;
#pragma unroll
    for (int c = 0; c < 4; ++c) {
      const int off = (wid * 4 + c) * 256;  // floats; dest 16B-aligned (sh+4)
      __builtin_amdgcn_global_load_lds((const as1_float*)(gb + off),
                                       (as3_float*)(sh + 4 + off), 16, 0, 0);
    }
  }
  if (tid < 4) sh[tid] = 0.f;                    // left zero pad
  if (tid >= 4 && tid < 8) sh[S_LEN + tid] = 0.f; // sh[16388..16391] = 0
  __syncthreads();

  for (int sq = 0; sq < 2; ++sq) {
    const int* dsc = ws + (g * 32 + wid * 2 + sq) * DSTRIDE;
    const int d  = sgpr_i(dsc[0]);
    const int p  = sgpr_i(dsc[1]);
    const int A  = sgpr_i(dsc[2]);
    const int B  = sgpr_i(dsc[3]);
    const int ci = sgpr_i(dsc[4]);
    const int t_ = sgpr_i(dsc[5]);
    const int h  = sgpr_i(dsc[6]);
    const int k  = sgpr_i(dsc[7]);
    const float invL = sgpr_f(((const float*)dsc)[8]);
    const float bval = sgpr_f(((const float*)dsc)[9]);
    float wf[11]; u64 wu[11];
#pragma unroll
    for (int t = 0; t < 11; ++t) {
      wf[t] = sgpr_f(((const float*)dsc)[10 + t]);
      const unsigned wb = (unsigned)__float_as_int(wf[t]);
      wu[t] = ((u64)wb << 32) | (u64)wb;   // wave-uniform -> SGPR pair
    }
    f2 bbv; bbv.x = bval; bbv.y = bval;    // persistent VGPR pair (c-operand)

    f2 mxv; mxv.x = -INFINITY; mxv.y = -INFINITY;
    float mxs = -INFINITY;
    int cw = 0;                            // wave-total count (uniform/SGPR)

    if (k == 7)
      conv_chunk<7 >(sh, wu, wf, bval, bbv, d, p, A, B, h, lane, mxv, mxs, cw);
    else if (k == 9)
      conv_chunk<9 >(sh, wu, wf, bval, bbv, d, p, A, B, h, lane, mxv, mxs, cw);
    else
      conv_chunk<11>(sh, wu, wf, bval, bbv, d, p, A, B, h, lane, mxv, mxs, cw);

    float mx = fmaxf(fmaxf(mxv.x, mxv.y), mxs);
#pragma unroll
    for (int off = 32; off > 0; off >>= 1)
      mx = fmaxf(mx, __shfl_down(mx, off, 64));
    if (lane == 0) {
      smx[h][t_] = mx; scn[h][t_] = cw;
      sci[t_] = ci; sin_[t_] = invL;       // same value from both chunks
    }
  }

  __syncthreads();
  if (tid < 16) {
    const float m = fmaxf(smx[0][tid], smx[1][tid]);
    const int   c = scn[0][tid] + scn[1][tid];
    out[(size_t)b * (2 * NCONV) + 2 * sci[tid]]     = m;
    out[(size_t)b * (2 * NCONV) + 2 * sci[tid] + 1] = (float)c * sin_[tid];
  }
}

extern "C" void kernel_launch(void* const* d_in, const int* in_sizes, int n_in,
                              void* d_out, int out_size, void* d_ws, size_t ws_size,
                              hipStream_t stream) {
  const float* x    = (const float*)d_in[0];
  const float* W    = (const float*)d_in[1];
  const float* bias = (const float*)d_in[2];
  const int*   ks   = (const int*)d_in[3];
  const int*   dil  = (const int*)d_in[4];
  const int*   pad  = (const int*)d_in[5];
  float* out = (float*)d_out;
  int*   ws  = (int*)d_ws;  // 8*32*24*4 = 24576 bytes

  hipLaunchKernelGGL(setup_desc, dim3(1), dim3(NCONV), 0, stream,
                     ks, dil, pad, W, bias, ws);
  hipLaunchKernelGGL(rocket_feats, dim3(NBATCH * NGRP), dim3(TPB), 0, stream,
                     x, ws, out);
}